// Round 12
// baseline (400.075 us; speedup 1.0000x reference)
//
#include <hip/hip_runtime.h>
#include <hip/hip_bf16.h>

#define T 128
#define CIN 128
#define C 256
#define NBE 1024            // B*E
#define MROWS (NBE * T)     // 131072 total rows

typedef short bf8_t __attribute__((ext_vector_type(8)));
typedef short s4_t __attribute__((ext_vector_type(4)));
typedef float f4_t __attribute__((ext_vector_type(4)));

__device__ inline short f2bf(float f) {
  union { float f; unsigned u; } v; v.f = f;
  unsigned r = v.u + 0x7FFFu + ((v.u >> 16) & 1u);
  return (short)(r >> 16);
}
__device__ inline float bf2f(short s) {
  union { unsigned u; float f; } v; v.u = ((unsigned)(unsigned short)s) << 16;
  return v.f;
}
__device__ inline f4_t mfma16(bf8_t a, bf8_t b, f4_t c) {
  return __builtin_amdgcn_mfma_f32_16x16x32_bf16(a, b, c, 0, 0, 0);
}
// LDS bf16 frag load, XOR-swizzled rows: short index col ^ ((row&7)<<3).
__device__ inline bf8_t lds_frag(const short* base, int row, int kcol, int rowc) {
  return *reinterpret_cast<const bf8_t*>(base + row * rowc + (kcol ^ ((row & 7) << 3)));
}

__global__ void prep_weights(const float* __restrict__ Wp, const float* __restrict__ Wb,
                             const float* __restrict__ Wg, const float* __restrict__ Wd,
                             short* __restrict__ ws) {
  int i = blockIdx.x * 256 + threadIdx.x;  // grid 256*256 = 65536
  if (i < 32768) ws[i] = f2bf(Wp[i]);      // Wp [256][128]
  ws[32768 + i]  = f2bf(Wb[i]);            // Wb [256][256]
  ws[98304 + i]  = f2bf(Wg[i]);
  ws[163840 + i] = f2bf(Wd[i]);
}

// ======================= K1: x = xe@Wp^T+bp ; u = x@Wb^T+bb ==============
// grid 2048 (64-row tiles), 256 thr (4 waves: 2 row-groups x 2 col-groups).
// LDS 48KB -> 3 blocks/CU. Writes x and u coalesced (bf16x8) to workspace.
__global__ __launch_bounds__(256, 1) void k1_proj(
    const float* __restrict__ xe, const short* __restrict__ wgt,
    const float* __restrict__ bp, const float* __restrict__ bb,
    short* __restrict__ xg, short* __restrict__ uS) {
  __shared__ __align__(16) short xe_s[64 * 128];  // 16KB
  __shared__ __align__(16) short x_s[64 * 256];   // 32KB (x, later u)

  const int tid = threadIdx.x;
  const int lane = tid & 63;
  const int w = tid >> 6;   // 0..3
  const int wr = w >> 1;    // 0..1: rows [wr*32, +32)
  const int wcg = w & 1;    // 0..1: cols [wcg*128, +128)
  const int l15 = lane & 15;
  const int l4 = lane >> 4;
  const int row0 = blockIdx.x * 64;

  const short* Wpb = wgt;          // [256][128]
  const short* Wbb = wgt + 32768;  // [256][256]

  // stage xe tile [64][128] fp32 -> bf16 swizzled
  {
    const float4* xe4 = reinterpret_cast<const float4*>(xe + (size_t)row0 * CIN);
#pragma unroll
    for (int j = 0; j < 8; ++j) {
      float4 v = xe4[j * 256 + tid];
      int fi = (j * 256 + tid) * 4;
      int r = fi >> 7, c = fi & 127;
      s4_t p = {f2bf(v.x), f2bf(v.y), f2bf(v.z), f2bf(v.w)};
      *reinterpret_cast<s4_t*>(&xe_s[r * 128 + (c ^ ((r & 7) << 3))]) = p;
    }
  }
  __syncthreads();

  const int row_a0 = wr * 32 + l15;
  const int colbase = wcg * 128 + l15;

  f4_t acc[2][8];
#pragma unroll
  for (int mi = 0; mi < 2; ++mi)
#pragma unroll
    for (int ni = 0; ni < 8; ++ni) acc[mi][ni] = (f4_t)(0.f);

  // GEMM1 (K=128)
#pragma unroll
  for (int kk = 0; kk < 4; ++kk) {
    int kcol = kk * 32 + l4 * 8;
    bf8_t a0 = lds_frag(xe_s, row_a0, kcol, 128);
    bf8_t a1 = lds_frag(xe_s, row_a0 + 16, kcol, 128);
#pragma unroll
    for (int ni = 0; ni < 8; ++ni) {
      bf8_t b = *reinterpret_cast<const bf8_t*>(Wpb + (colbase + ni * 16) * 128 + kcol);
      acc[0][ni] = mfma16(a0, b, acc[0][ni]);
      acc[1][ni] = mfma16(a1, b, acc[1][ni]);
    }
  }
  // x (+bp) -> x_s swizzled
#pragma unroll
  for (int ni = 0; ni < 8; ++ni) {
    int col = colbase + ni * 16;
    float bias = bp[col];
#pragma unroll
    for (int mi = 0; mi < 2; ++mi)
#pragma unroll
      for (int r = 0; r < 4; ++r) {
        int row = wr * 32 + mi * 16 + l4 * 4 + r;
        x_s[row * 256 + (col ^ ((row & 7) << 3))] = f2bf(acc[mi][ni][r] + bias);
      }
  }
  __syncthreads();

  // GEMM2 (K=256): acc = u (kept in regs across the xg store)
#pragma unroll
  for (int mi = 0; mi < 2; ++mi)
#pragma unroll
    for (int ni = 0; ni < 8; ++ni) acc[mi][ni] = (f4_t)(0.f);
#pragma unroll
  for (int kk = 0; kk < 8; ++kk) {
    int kcol = kk * 32 + l4 * 8;
    bf8_t a0 = lds_frag(x_s, row_a0, kcol, 256);
    bf8_t a1 = lds_frag(x_s, row_a0 + 16, kcol, 256);
#pragma unroll
    for (int ni = 0; ni < 8; ++ni) {
      bf8_t b = *reinterpret_cast<const bf8_t*>(Wbb + (colbase + ni * 16) * 256 + kcol);
      acc[0][ni] = mfma16(a0, b, acc[0][ni]);
      acc[1][ni] = mfma16(a1, b, acc[1][ni]);
    }
  }
  // x_s -> xg coalesced (bf16x8); all x_s reads complete after this
#pragma unroll
  for (int j = 0; j < 8; ++j) {
    int chunk = j * 256 + tid;          // 2048 chunks = 64 rows * 32
    int r = chunk >> 5, c8 = chunk & 31;
    bf8_t v = *reinterpret_cast<const bf8_t*>(&x_s[r * 256 + ((c8 * 8) ^ ((r & 7) << 3))]);
    *reinterpret_cast<bf8_t*>(&xg[(size_t)(row0 + r) * 256 + c8 * 8]) = v;
  }
  __syncthreads();  // x_s dead -> reuse for u staging

  // u (+bb) -> x_s swizzled, then coalesced store to uS
#pragma unroll
  for (int ni = 0; ni < 8; ++ni) {
    int col = colbase + ni * 16;
    float bias = bb[col];
#pragma unroll
    for (int mi = 0; mi < 2; ++mi)
#pragma unroll
      for (int r = 0; r < 4; ++r) {
        int row = wr * 32 + mi * 16 + l4 * 4 + r;
        x_s[row * 256 + (col ^ ((row & 7) << 3))] = f2bf(acc[mi][ni][r] + bias);
      }
  }
  __syncthreads();
#pragma unroll
  for (int j = 0; j < 8; ++j) {
    int chunk = j * 256 + tid;
    int r = chunk >> 5, c8 = chunk & 31;
    bf8_t v = *reinterpret_cast<const bf8_t*>(&x_s[r * 256 + ((c8 * 8) ^ ((r & 7) << 3))]);
    *reinterpret_cast<bf8_t*>(&uS[(size_t)(row0 + r) * 256 + c8 * 8]) = v;
  }
}

// ======================= K2: in-place scan u -> S ========================
// grid NBE, 256 thr (one per channel). Coalesced 2B accesses; 4-deep ring.
__global__ __launch_bounds__(256, 1) void k2_scan(
    const float* __restrict__ ap, short* __restrict__ uS) {
  const int be = blockIdx.x;
  const int c = threadIdx.x;
  short* p = uS + (size_t)be * T * C + c;
  float a = tanhf(ap[c]);
  float un[4];
#pragma unroll
  for (int j = 0; j < 4; ++j) un[j] = bf2f(p[j * C]);
  float s = 0.f;
#pragma unroll 4
  for (int t = 0; t < T; ++t) {
    float nx = (t + 4 < T) ? bf2f(p[(t + 4) * C]) : 0.f;
    s = a * s + un[0];
    p[t * C] = f2bf(s);
    un[0] = un[1]; un[1] = un[2]; un[2] = un[3]; un[3] = nx;
  }
}

// ============ K3: y = S@Wg^T + x@Wd^T + biases; BN; GELU; +x =============
// grid 2048 (64-row tiles), 256 thr. LDS 64KB -> 2 blocks/CU.
__global__ __launch_bounds__(256, 1) void k3_out(
    const short* __restrict__ wgt, const short* __restrict__ xg,
    const short* __restrict__ uS, const float* __restrict__ bg,
    const float* __restrict__ bd, const float* __restrict__ gamma,
    const float* __restrict__ beta, const float* __restrict__ rmean,
    const float* __restrict__ rvar, float* __restrict__ out) {
  __shared__ __align__(16) short lds2[2][64 * 256];  // [0]=S, [1]=x; 64KB
  float* fbuf = reinterpret_cast<float*>(lds2);

  const int tid = threadIdx.x;
  const int lane = tid & 63;
  const int w = tid >> 6;
  const int wr = w >> 1;
  const int wcg = w & 1;
  const int l15 = lane & 15;
  const int l4 = lane >> 4;
  const int row0 = blockIdx.x * 64;

  const short* Wgb = wgt + 98304;
  const short* Wdb = wgt + 163840;

  // stage S and x tiles (coalesced bf16x8 -> swizzled LDS)
#pragma unroll
  for (int j = 0; j < 8; ++j) {
    int chunk = j * 256 + tid;
    int r = chunk >> 5, c8 = chunk & 31;
    int loff = r * 256 + ((c8 * 8) ^ ((r & 7) << 3));
    size_t goff = (size_t)(row0 + r) * 256 + c8 * 8;
    *reinterpret_cast<bf8_t*>(&lds2[0][loff]) =
        *reinterpret_cast<const bf8_t*>(&uS[goff]);
    *reinterpret_cast<bf8_t*>(&lds2[1][loff]) =
        *reinterpret_cast<const bf8_t*>(&xg[goff]);
  }
  __syncthreads();

  const int row_a0 = wr * 32 + l15;
  const int colbase = wcg * 128 + l15;

  f4_t acc[2][8];
#pragma unroll
  for (int mi = 0; mi < 2; ++mi)
#pragma unroll
    for (int ni = 0; ni < 8; ++ni) acc[mi][ni] = (f4_t)(0.f);

#pragma unroll
  for (int kk = 0; kk < 8; ++kk) {
    int kcol = kk * 32 + l4 * 8;
    bf8_t s0 = lds_frag(lds2[0], row_a0, kcol, 256);
    bf8_t s1 = lds_frag(lds2[0], row_a0 + 16, kcol, 256);
    bf8_t x0 = lds_frag(lds2[1], row_a0, kcol, 256);
    bf8_t x1 = lds_frag(lds2[1], row_a0 + 16, kcol, 256);
#pragma unroll
    for (int ni = 0; ni < 8; ++ni) {
      bf8_t bgf = *reinterpret_cast<const bf8_t*>(Wgb + (colbase + ni * 16) * 256 + kcol);
      acc[0][ni] = mfma16(s0, bgf, acc[0][ni]);
      acc[1][ni] = mfma16(s1, bgf, acc[1][ni]);
      bf8_t bdf = *reinterpret_cast<const bf8_t*>(Wdb + (colbase + ni * 16) * 256 + kcol);
      acc[0][ni] = mfma16(x0, bdf, acc[0][ni]);
      acc[1][ni] = mfma16(x1, bdf, acc[1][ni]);
    }
  }

  // epilogue into acc (reads x residual from lds2[1])
#pragma unroll
  for (int ni = 0; ni < 8; ++ni) {
    int col = colbase + ni * 16;
    float bsum = bg[col] + bd[col];
    float mu = rmean[col];
    float rstd = rsqrtf(rvar[col] + 1e-5f);
    float ga = gamma[col], bt = beta[col];
#pragma unroll
    for (int mi = 0; mi < 2; ++mi)
#pragma unroll
      for (int r = 0; r < 4; ++r) {
        int row = wr * 32 + mi * 16 + l4 * 4 + r;
        float y = acc[mi][ni][r] + bsum;
        y = (y - mu) * rstd * ga + bt;
        float g = 0.5f * y * (1.f + erff(y * 0.70710678118654752f));
        float xv = bf2f(lds2[1][row * 256 + (col ^ ((row & 7) << 3))]);
        acc[mi][ni][r] = g + xv;
      }
  }
  __syncthreads();

  // stage fp32 out tile (swizzle col ^ (l4<<4)), coalesced float4 out
#pragma unroll
  for (int ni = 0; ni < 8; ++ni) {
    int col = colbase + ni * 16;
#pragma unroll
    for (int mi = 0; mi < 2; ++mi)
#pragma unroll
      for (int r = 0; r < 4; ++r) {
        int row = wr * 32 + mi * 16 + l4 * 4 + r;  // (row>>2)&3 == l4
        fbuf[row * 256 + (col ^ (l4 << 4))] = acc[mi][ni][r];
      }
  }
  __syncthreads();

  // BUGFIX r10: 64 rows x 256 fp32 = 4096 float4 -> j<16 (was j<8: rows
  // 32-63 never stored -> absmax 4.06 = max|ref|).
  float4* out4 = reinterpret_cast<float4*>(out + (size_t)row0 * 256);
#pragma unroll
  for (int j = 0; j < 16; ++j) {
    int f4i = j * 256 + tid;
    int row = f4i >> 6;
    int c4 = (f4i & 63) << 2;
    int sc = c4 ^ (((row >> 2) & 3) << 4);
    out4[f4i] = *reinterpret_cast<float4*>(&fbuf[row * 256 + sc]);
  }
}

// =============== fallback: round-1 proven fused kernel (298us) ===========
__global__ __launch_bounds__(512, 1) void fused_fallback(
    const float* __restrict__ xe, const short* __restrict__ wgt,
    const float* __restrict__ bp, const float* __restrict__ a_param,
    const float* __restrict__ bb, const float* __restrict__ bg,
    const float* __restrict__ bd, const float* __restrict__ gamma,
    const float* __restrict__ beta, const float* __restrict__ rmean,
    const float* __restrict__ rvar, float* __restrict__ out) {
  __shared__ __align__(16) short lds_x[T * C];
  __shared__ __align__(16) short lds_u[T * C];
  short* lds_xe = lds_u;

  const int tid = threadIdx.x;
  const int lane = tid & 63;
  const int w = tid >> 6;
  const int wr = w >> 1;
  const int wc = w & 1;
  const int l15 = lane & 15;
  const int l4 = lane >> 4;
  const int be = blockIdx.x;

  const float* xe_blk = xe + (size_t)be * T * CIN;
  float* out_blk = out + (size_t)be * T * C;

  const short* Wpb = wgt;
  const short* Wbb = wgt + 32768;
  const short* Wgb = wgt + 98304;
  const short* Wdb = wgt + 163840;

#pragma unroll
  for (int j = 0; j < 32; ++j) {
    int idx = j * 512 + tid;
    int r = idx >> 7, c = idx & 127;
    lds_xe[r * 128 + (c ^ ((r & 7) << 3))] = f2bf(xe_blk[idx]);
  }
  __syncthreads();

  const int row_a0 = wr * 32 + l15;
  const int col0 = wc * 128 + l15;
  f4_t acc[2][8];

#pragma unroll
  for (int mi = 0; mi < 2; ++mi)
#pragma unroll
    for (int ni = 0; ni < 8; ++ni) acc[mi][ni] = (f4_t)(0.f);
#pragma unroll
  for (int kk = 0; kk < 4; ++kk) {
    int kcol = kk * 32 + l4 * 8;
    bf8_t a0 = lds_frag(lds_xe, row_a0, kcol, 128);
    bf8_t a1 = lds_frag(lds_xe, row_a0 + 16, kcol, 128);
#pragma unroll
    for (int ni = 0; ni < 8; ++ni) {
      bf8_t b = *reinterpret_cast<const bf8_t*>(Wpb + (col0 + ni * 16) * 128 + kcol);
      acc[0][ni] = mfma16(a0, b, acc[0][ni]);
      acc[1][ni] = mfma16(a1, b, acc[1][ni]);
    }
  }
#pragma unroll
  for (int ni = 0; ni < 8; ++ni) {
    int col = col0 + ni * 16;
    float bias = bp[col];
#pragma unroll
    for (int mi = 0; mi < 2; ++mi)
#pragma unroll
      for (int r = 0; r < 4; ++r) {
        int row = wr * 32 + mi * 16 + l4 * 4 + r;
        lds_x[row * 256 + (col ^ ((row & 7) << 3))] = f2bf(acc[mi][ni][r] + bias);
      }
  }
  __syncthreads();

#pragma unroll
  for (int mi = 0; mi < 2; ++mi)
#pragma unroll
    for (int ni = 0; ni < 8; ++ni) acc[mi][ni] = (f4_t)(0.f);
#pragma unroll
  for (int kk = 0; kk < 8; ++kk) {
    int kcol = kk * 32 + l4 * 8;
    bf8_t a0 = lds_frag(lds_x, row_a0, kcol, 256);
    bf8_t a1 = lds_frag(lds_x, row_a0 + 16, kcol, 256);
#pragma unroll
    for (int ni = 0; ni < 8; ++ni) {
      bf8_t b = *reinterpret_cast<const bf8_t*>(Wbb + (col0 + ni * 16) * 256 + kcol);
      acc[0][ni] = mfma16(a0, b, acc[0][ni]);
      acc[1][ni] = mfma16(a1, b, acc[1][ni]);
    }
  }
#pragma unroll
  for (int ni = 0; ni < 8; ++ni) {
    int col = col0 + ni * 16;
    float bias = bb[col];
#pragma unroll
    for (int mi = 0; mi < 2; ++mi)
#pragma unroll
      for (int r = 0; r < 4; ++r) {
        int row = wr * 32 + mi * 16 + l4 * 4 + r;
        lds_u[row * 256 + (col ^ ((row & 7) << 3))] = f2bf(acc[mi][ni][r] + bias);
      }
  }
  __syncthreads();

  if (tid < 256) {
    float a = tanhf(a_param[tid]);
    float s = 0.f;
    float un = bf2f(lds_u[tid]);
#pragma unroll 8
    for (int t = 0; t < 128; ++t) {
      float unn = (t < 127) ? bf2f(lds_u[(t + 1) * 256 + (tid ^ (((t + 1) & 7) << 3))]) : 0.f;
      s = a * s + un;
      lds_u[t * 256 + (tid ^ ((t & 7) << 3))] = f2bf(s);
      un = unn;
    }
  }
  __syncthreads();

#pragma unroll
  for (int mi = 0; mi < 2; ++mi)
#pragma unroll
    for (int ni = 0; ni < 8; ++ni) acc[mi][ni] = (f4_t)(0.f);
#pragma unroll
  for (int kk = 0; kk < 8; ++kk) {
    int kcol = kk * 32 + l4 * 8;
    bf8_t s0 = lds_frag(lds_u, row_a0, kcol, 256);
    bf8_t s1 = lds_frag(lds_u, row_a0 + 16, kcol, 256);
    bf8_t x0 = lds_frag(lds_x, row_a0, kcol, 256);
    bf8_t x1 = lds_frag(lds_x, row_a0 + 16, kcol, 256);
#pragma unroll
    for (int ni = 0; ni < 8; ++ni) {
      bf8_t bgf = *reinterpret_cast<const bf8_t*>(Wgb + (col0 + ni * 16) * 256 + kcol);
      acc[0][ni] = mfma16(s0, bgf, acc[0][ni]);
      acc[1][ni] = mfma16(s1, bgf, acc[1][ni]);
      bf8_t bdf = *reinterpret_cast<const bf8_t*>(Wdb + (col0 + ni * 16) * 256 + kcol);
      acc[0][ni] = mfma16(x0, bdf, acc[0][ni]);
      acc[1][ni] = mfma16(x1, bdf, acc[1][ni]);
    }
  }

#pragma unroll
  for (int ni = 0; ni < 8; ++ni) {
    int col = col0 + ni * 16;
    float bsum = bg[col] + bd[col];
    float mu = rmean[col];
    float rstd = rsqrtf(rvar[col] + 1e-5f);
    float ga = gamma[col], bt = beta[col];
#pragma unroll
    for (int mi = 0; mi < 2; ++mi)
#pragma unroll
      for (int r = 0; r < 4; ++r) {
        int row = wr * 32 + mi * 16 + l4 * 4 + r;
        float y = acc[mi][ni][r] + bsum;
        y = (y - mu) * rstd * ga + bt;
        float g = 0.5f * y * (1.f + erff(y * 0.70710678118654752f));
        float xv = bf2f(lds_x[row * 256 + (col ^ ((row & 7) << 3))]);
        out_blk[row * 256 + col] = g + xv;
      }
  }
}

extern "C" void kernel_launch(void* const* d_in, const int* in_sizes, int n_in,
                              void* d_out, int out_size, void* d_ws, size_t ws_size,
                              hipStream_t stream) {
  const float* xe    = (const float*)d_in[0];
  const float* Wp    = (const float*)d_in[1];
  const float* bp    = (const float*)d_in[2];
  const float* ap    = (const float*)d_in[3];
  const float* Wb    = (const float*)d_in[4];
  const float* bb    = (const float*)d_in[5];
  const float* Wg    = (const float*)d_in[6];
  const float* bg    = (const float*)d_in[7];
  const float* Wd    = (const float*)d_in[8];
  const float* bd    = (const float*)d_in[9];
  const float* gamma = (const float*)d_in[10];
  const float* beta  = (const float*)d_in[11];
  const float* rmean = (const float*)d_in[12];
  const float* rvar  = (const float*)d_in[13];
  float* out = (float*)d_out;

  short* wgt = (short*)d_ws;                       // 458752 B bf16 weights
  const size_t XG_OFF = 458752;                    // x bf16: 64 MiB
  const size_t US_OFF = XG_OFF + (size_t)MROWS * C * 2;
  const size_t NEED = US_OFF + (size_t)MROWS * C * 2;

  prep_weights<<<256, 256, 0, stream>>>(Wp, Wb, Wg, Wd, wgt);

  if (ws_size >= NEED) {
    short* xg = (short*)((char*)d_ws + XG_OFF);
    short* uS = (short*)((char*)d_ws + US_OFF);
    k1_proj<<<MROWS / 64, 256, 0, stream>>>(xe, wgt, bp, bb, xg, uS);
    k2_scan<<<NBE, 256, 0, stream>>>(ap, uS);
    k3_out<<<MROWS / 64, 256, 0, stream>>>(wgt, xg, uS, bg, bd, gamma, beta,
                                           rmean, rvar, out);
  } else {
    fused_fallback<<<NBE, 512, 0, stream>>>(xe, wgt, bp, ap, bb, bg, bd, gamma,
                                            beta, rmean, rvar, out);
  }
}

// Round 13
// 372.075 us; speedup vs baseline: 1.0753x; 1.0753x over previous
//
#include <hip/hip_runtime.h>
#include <hip/hip_bf16.h>

#define T 128
#define CIN 128
#define C 256
#define NBE 1024            // B*E
#define MROWS (NBE * T)     // 131072 total rows

typedef short bf8_t __attribute__((ext_vector_type(8)));
typedef short s4_t __attribute__((ext_vector_type(4)));
typedef float f4_t __attribute__((ext_vector_type(4)));

__device__ inline short f2bf(float f) {
  union { float f; unsigned u; } v; v.f = f;
  unsigned r = v.u + 0x7FFFu + ((v.u >> 16) & 1u);
  return (short)(r >> 16);
}
__device__ inline float bf2f(short s) {
  union { unsigned u; float f; } v; v.u = ((unsigned)(unsigned short)s) << 16;
  return v.f;
}
__device__ inline f4_t mfma16(bf8_t a, bf8_t b, f4_t c) {
  return __builtin_amdgcn_mfma_f32_16x16x32_bf16(a, b, c, 0, 0, 0);
}
// LDS bf16 frag load, XOR-swizzled rows: short index col ^ ((row&7)<<3).
__device__ inline bf8_t lds_frag(const short* base, int row, int kcol, int rowc) {
  return *reinterpret_cast<const bf8_t*>(base + row * rowc + (kcol ^ ((row & 7) << 3)));
}

__global__ void prep_weights(const float* __restrict__ Wp, const float* __restrict__ Wb,
                             const float* __restrict__ Wg, const float* __restrict__ Wd,
                             short* __restrict__ ws) {
  int i = blockIdx.x * 256 + threadIdx.x;  // grid 256*256 = 65536
  if (i < 32768) ws[i] = f2bf(Wp[i]);      // Wp [256][128]
  ws[32768 + i]  = f2bf(Wb[i]);            // Wb [256][256]
  ws[98304 + i]  = f2bf(Wg[i]);
  ws[163840 + i] = f2bf(Wd[i]);
}

// ======================= K1: x = xe@Wp^T+bp ; u = x@Wb^T+bb ==============
// grid 2048 (64-row tiles), 256 thr. LDS 48KB -> 3 blocks/CU.
__global__ __launch_bounds__(256, 1) void k1_proj(
    const float* __restrict__ xe, const short* __restrict__ wgt,
    const float* __restrict__ bp, const float* __restrict__ bb,
    short* __restrict__ xg, short* __restrict__ uS) {
  __shared__ __align__(16) short xe_s[64 * 128];  // 16KB
  __shared__ __align__(16) short x_s[64 * 256];   // 32KB (x, later u)

  const int tid = threadIdx.x;
  const int lane = tid & 63;
  const int w = tid >> 6;   // 0..3
  const int wr = w >> 1;    // 0..1: rows [wr*32, +32)
  const int wcg = w & 1;    // 0..1: cols [wcg*128, +128)
  const int l15 = lane & 15;
  const int l4 = lane >> 4;
  const int row0 = blockIdx.x * 64;

  const short* Wpb = wgt;          // [256][128]
  const short* Wbb = wgt + 32768;  // [256][256]

  // stage xe tile [64][128] fp32 -> bf16 swizzled
  {
    const float4* xe4 = reinterpret_cast<const float4*>(xe + (size_t)row0 * CIN);
#pragma unroll
    for (int j = 0; j < 8; ++j) {
      float4 v = xe4[j * 256 + tid];
      int fi = (j * 256 + tid) * 4;
      int r = fi >> 7, c = fi & 127;
      s4_t p = {f2bf(v.x), f2bf(v.y), f2bf(v.z), f2bf(v.w)};
      *reinterpret_cast<s4_t*>(&xe_s[r * 128 + (c ^ ((r & 7) << 3))]) = p;
    }
  }
  __syncthreads();

  const int row_a0 = wr * 32 + l15;
  const int colbase = wcg * 128 + l15;

  f4_t acc[2][8];
#pragma unroll
  for (int mi = 0; mi < 2; ++mi)
#pragma unroll
    for (int ni = 0; ni < 8; ++ni) acc[mi][ni] = (f4_t)(0.f);

  // GEMM1 (K=128)
#pragma unroll
  for (int kk = 0; kk < 4; ++kk) {
    int kcol = kk * 32 + l4 * 8;
    bf8_t a0 = lds_frag(xe_s, row_a0, kcol, 128);
    bf8_t a1 = lds_frag(xe_s, row_a0 + 16, kcol, 128);
#pragma unroll
    for (int ni = 0; ni < 8; ++ni) {
      bf8_t b = *reinterpret_cast<const bf8_t*>(Wpb + (colbase + ni * 16) * 128 + kcol);
      acc[0][ni] = mfma16(a0, b, acc[0][ni]);
      acc[1][ni] = mfma16(a1, b, acc[1][ni]);
    }
  }
  // x (+bp) -> x_s swizzled
#pragma unroll
  for (int ni = 0; ni < 8; ++ni) {
    int col = colbase + ni * 16;
    float bias = bp[col];
#pragma unroll
    for (int mi = 0; mi < 2; ++mi)
#pragma unroll
      for (int r = 0; r < 4; ++r) {
        int row = wr * 32 + mi * 16 + l4 * 4 + r;
        x_s[row * 256 + (col ^ ((row & 7) << 3))] = f2bf(acc[mi][ni][r] + bias);
      }
  }
  __syncthreads();

  // GEMM2 (K=256): acc = u (kept in regs across the xg store)
#pragma unroll
  for (int mi = 0; mi < 2; ++mi)
#pragma unroll
    for (int ni = 0; ni < 8; ++ni) acc[mi][ni] = (f4_t)(0.f);
#pragma unroll
  for (int kk = 0; kk < 8; ++kk) {
    int kcol = kk * 32 + l4 * 8;
    bf8_t a0 = lds_frag(x_s, row_a0, kcol, 256);
    bf8_t a1 = lds_frag(x_s, row_a0 + 16, kcol, 256);
#pragma unroll
    for (int ni = 0; ni < 8; ++ni) {
      bf8_t b = *reinterpret_cast<const bf8_t*>(Wbb + (colbase + ni * 16) * 256 + kcol);
      acc[0][ni] = mfma16(a0, b, acc[0][ni]);
      acc[1][ni] = mfma16(a1, b, acc[1][ni]);
    }
  }
  // x_s -> xg coalesced (bf16x8)
#pragma unroll
  for (int j = 0; j < 8; ++j) {
    int chunk = j * 256 + tid;          // 2048 chunks = 64 rows * 32
    int r = chunk >> 5, c8 = chunk & 31;
    bf8_t v = *reinterpret_cast<const bf8_t*>(&x_s[r * 256 + ((c8 * 8) ^ ((r & 7) << 3))]);
    *reinterpret_cast<bf8_t*>(&xg[(size_t)(row0 + r) * 256 + c8 * 8]) = v;
  }
  __syncthreads();  // x_s dead -> reuse for u staging

  // u (+bb) -> x_s swizzled, then coalesced store to uS
#pragma unroll
  for (int ni = 0; ni < 8; ++ni) {
    int col = colbase + ni * 16;
    float bias = bb[col];
#pragma unroll
    for (int mi = 0; mi < 2; ++mi)
#pragma unroll
      for (int r = 0; r < 4; ++r) {
        int row = wr * 32 + mi * 16 + l4 * 4 + r;
        x_s[row * 256 + (col ^ ((row & 7) << 3))] = f2bf(acc[mi][ni][r] + bias);
      }
  }
  __syncthreads();
#pragma unroll
  for (int j = 0; j < 8; ++j) {
    int chunk = j * 256 + tid;
    int r = chunk >> 5, c8 = chunk & 31;
    bf8_t v = *reinterpret_cast<const bf8_t*>(&x_s[r * 256 + ((c8 * 8) ^ ((r & 7) << 3))]);
    *reinterpret_cast<bf8_t*>(&uS[(size_t)(row0 + r) * 256 + c8 * 8]) = v;
  }
}

// ======================= K2: in-place scan u -> S ========================
__global__ __launch_bounds__(256, 1) void k2_scan(
    const float* __restrict__ ap, short* __restrict__ uS) {
  const int be = blockIdx.x;
  const int c = threadIdx.x;
  short* p = uS + (size_t)be * T * C + c;
  float a = tanhf(ap[c]);
  float un[4];
#pragma unroll
  for (int j = 0; j < 4; ++j) un[j] = bf2f(p[j * C]);
  float s = 0.f;
#pragma unroll 4
  for (int t = 0; t < T; ++t) {
    float nx = (t + 4 < T) ? bf2f(p[(t + 4) * C]) : 0.f;
    s = a * s + un[0];
    p[t * C] = f2bf(s);
    un[0] = un[1]; un[1] = un[2]; un[2] = un[3]; un[3] = nx;
  }
}

// ===== K3 (no-LDS): y = S@Wg^T + x@Wd^T + biases; BN; GELU; +x ==========
// r12 post-mortem: LDS-staged k3 ran at 1 blk/CU (Occ 11.6%) -> 1 wave/SIMD,
// latency-naked (MfmaUtil 4.8%, 281us). This version: ZERO LDS, zero
// barriers; A-frags (S, x) read directly from global (L3/L2-resident),
// B-frags from L2-resident weights. 32-row tiles, grid 4096, 4 waves = 4
// col-groups. waves_per_eu(4) caps VGPR at 128 -> 4 waves/SIMD target.
__global__ __launch_bounds__(256, 1) __attribute__((amdgpu_waves_per_eu(4)))
void k3_nolds(
    const short* __restrict__ wgt, const short* __restrict__ xg,
    const short* __restrict__ uS, const float* __restrict__ bg,
    const float* __restrict__ bd, const float* __restrict__ gamma,
    const float* __restrict__ beta, const float* __restrict__ rmean,
    const float* __restrict__ rvar, float* __restrict__ out) {
  const int tid = threadIdx.x;
  const int lane = tid & 63;
  const int w = tid >> 6;          // 0..3: col group [w*64, +64)
  const int l15 = lane & 15;
  const int l4 = lane >> 4;        // 0..3
  const int row0 = blockIdx.x * 32;

  const short* Wgb = wgt + 98304;   // [256][256]
  const short* Wdb = wgt + 163840;  // [256][256]
  const int colbase = w * 64 + l15;

  const short* Sb = uS + (size_t)row0 * 256;  // A rows for S
  const short* Xb = xg + (size_t)row0 * 256;  // A rows for x

  f4_t acc[2][4];
#pragma unroll
  for (int mi = 0; mi < 2; ++mi)
#pragma unroll
    for (int ni = 0; ni < 4; ++ni) acc[mi][ni] = (f4_t)(0.f);

#pragma unroll
  for (int kk = 0; kk < 8; ++kk) {
    const int kcol = kk * 32 + l4 * 8;
    // S rows (16 B/lane direct global; rows l15 / l15+16)
    bf8_t s0 = *reinterpret_cast<const bf8_t*>(Sb + l15 * 256 + kcol);
    bf8_t s1 = *reinterpret_cast<const bf8_t*>(Sb + (l15 + 16) * 256 + kcol);
#pragma unroll
    for (int ni = 0; ni < 4; ++ni) {
      bf8_t bgf = *reinterpret_cast<const bf8_t*>(Wgb + (colbase + ni * 16) * 256 + kcol);
      acc[0][ni] = mfma16(s0, bgf, acc[0][ni]);
      acc[1][ni] = mfma16(s1, bgf, acc[1][ni]);
    }
    bf8_t x0 = *reinterpret_cast<const bf8_t*>(Xb + l15 * 256 + kcol);
    bf8_t x1 = *reinterpret_cast<const bf8_t*>(Xb + (l15 + 16) * 256 + kcol);
#pragma unroll
    for (int ni = 0; ni < 4; ++ni) {
      bf8_t bdf = *reinterpret_cast<const bf8_t*>(Wdb + (colbase + ni * 16) * 256 + kcol);
      acc[0][ni] = mfma16(x0, bdf, acc[0][ni]);
      acc[1][ni] = mfma16(x1, bdf, acc[1][ni]);
    }
  }

  // epilogue: +bg+bd, BN(eval), exact GELU, +x; scattered fp32 stores
  // (r1 measured scatter amp 1.34x ~ +7us -- cheaper than LDS+barriers).
#pragma unroll
  for (int ni = 0; ni < 4; ++ni) {
    const int col = colbase + ni * 16;
    float bsum = bg[col] + bd[col];
    float mu = rmean[col];
    float rstd = rsqrtf(rvar[col] + 1e-5f);
    float ga = gamma[col], bt = beta[col];
#pragma unroll
    for (int mi = 0; mi < 2; ++mi)
#pragma unroll
      for (int r = 0; r < 4; ++r) {
        int row = row0 + mi * 16 + l4 * 4 + r;
        float y = acc[mi][ni][r] + bsum;
        y = (y - mu) * rstd * ga + bt;
        float g = 0.5f * y * (1.f + erff(y * 0.70710678118654752f));
        float xv = bf2f(xg[(size_t)row * 256 + col]);
        out[(size_t)row * 256 + col] = g + xv;
      }
  }
}

// =============== fallback: round-1 proven fused kernel (298us) ===========
__global__ __launch_bounds__(512, 1) void fused_fallback(
    const float* __restrict__ xe, const short* __restrict__ wgt,
    const float* __restrict__ bp, const float* __restrict__ a_param,
    const float* __restrict__ bb, const float* __restrict__ bg,
    const float* __restrict__ bd, const float* __restrict__ gamma,
    const float* __restrict__ beta, const float* __restrict__ rmean,
    const float* __restrict__ rvar, float* __restrict__ out) {
  __shared__ __align__(16) short lds_x[T * C];
  __shared__ __align__(16) short lds_u[T * C];
  short* lds_xe = lds_u;

  const int tid = threadIdx.x;
  const int lane = tid & 63;
  const int w = tid >> 6;
  const int wr = w >> 1;
  const int wc = w & 1;
  const int l15 = lane & 15;
  const int l4 = lane >> 4;
  const int be = blockIdx.x;

  const float* xe_blk = xe + (size_t)be * T * CIN;
  float* out_blk = out + (size_t)be * T * C;

  const short* Wpb = wgt;
  const short* Wbb = wgt + 32768;
  const short* Wgb = wgt + 98304;
  const short* Wdb = wgt + 163840;

#pragma unroll
  for (int j = 0; j < 32; ++j) {
    int idx = j * 512 + tid;
    int r = idx >> 7, c = idx & 127;
    lds_xe[r * 128 + (c ^ ((r & 7) << 3))] = f2bf(xe_blk[idx]);
  }
  __syncthreads();

  const int row_a0 = wr * 32 + l15;
  const int col0 = wc * 128 + l15;
  f4_t acc[2][8];

#pragma unroll
  for (int mi = 0; mi < 2; ++mi)
#pragma unroll
    for (int ni = 0; ni < 8; ++ni) acc[mi][ni] = (f4_t)(0.f);
#pragma unroll
  for (int kk = 0; kk < 4; ++kk) {
    int kcol = kk * 32 + l4 * 8;
    bf8_t a0 = lds_frag(lds_xe, row_a0, kcol, 128);
    bf8_t a1 = lds_frag(lds_xe, row_a0 + 16, kcol, 128);
#pragma unroll
    for (int ni = 0; ni < 8; ++ni) {
      bf8_t b = *reinterpret_cast<const bf8_t*>(Wpb + (col0 + ni * 16) * 128 + kcol);
      acc[0][ni] = mfma16(a0, b, acc[0][ni]);
      acc[1][ni] = mfma16(a1, b, acc[1][ni]);
    }
  }
#pragma unroll
  for (int ni = 0; ni < 8; ++ni) {
    int col = col0 + ni * 16;
    float bias = bp[col];
#pragma unroll
    for (int mi = 0; mi < 2; ++mi)
#pragma unroll
      for (int r = 0; r < 4; ++r) {
        int row = wr * 32 + mi * 16 + l4 * 4 + r;
        lds_x[row * 256 + (col ^ ((row & 7) << 3))] = f2bf(acc[mi][ni][r] + bias);
      }
  }
  __syncthreads();

#pragma unroll
  for (int mi = 0; mi < 2; ++mi)
#pragma unroll
    for (int ni = 0; ni < 8; ++ni) acc[mi][ni] = (f4_t)(0.f);
#pragma unroll
  for (int kk = 0; kk < 8; ++kk) {
    int kcol = kk * 32 + l4 * 8;
    bf8_t a0 = lds_frag(lds_x, row_a0, kcol, 256);
    bf8_t a1 = lds_frag(lds_x, row_a0 + 16, kcol, 256);
#pragma unroll
    for (int ni = 0; ni < 8; ++ni) {
      bf8_t b = *reinterpret_cast<const bf8_t*>(Wbb + (col0 + ni * 16) * 256 + kcol);
      acc[0][ni] = mfma16(a0, b, acc[0][ni]);
      acc[1][ni] = mfma16(a1, b, acc[1][ni]);
    }
  }
#pragma unroll
  for (int ni = 0; ni < 8; ++ni) {
    int col = col0 + ni * 16;
    float bias = bb[col];
#pragma unroll
    for (int mi = 0; mi < 2; ++mi)
#pragma unroll
      for (int r = 0; r < 4; ++r) {
        int row = wr * 32 + mi * 16 + l4 * 4 + r;
        lds_u[row * 256 + (col ^ ((row & 7) << 3))] = f2bf(acc[mi][ni][r] + bias);
      }
  }
  __syncthreads();

  if (tid < 256) {
    float a = tanhf(a_param[tid]);
    float s = 0.f;
    float un = bf2f(lds_u[tid]);
#pragma unroll 8
    for (int t = 0; t < 128; ++t) {
      float unn = (t < 127) ? bf2f(lds_u[(t + 1) * 256 + (tid ^ (((t + 1) & 7) << 3))]) : 0.f;
      s = a * s + un;
      lds_u[t * 256 + (tid ^ ((t & 7) << 3))] = f2bf(s);
      un = unn;
    }
  }
  __syncthreads();

#pragma unroll
  for (int mi = 0; mi < 2; ++mi)
#pragma unroll
    for (int ni = 0; ni < 8; ++ni) acc[mi][ni] = (f4_t)(0.f);
#pragma unroll
  for (int kk = 0; kk < 8; ++kk) {
    int kcol = kk * 32 + l4 * 8;
    bf8_t s0 = lds_frag(lds_u, row_a0, kcol, 256);
    bf8_t s1 = lds_frag(lds_u, row_a0 + 16, kcol, 256);
    bf8_t x0 = lds_frag(lds_x, row_a0, kcol, 256);
    bf8_t x1 = lds_frag(lds_x, row_a0 + 16, kcol, 256);
#pragma unroll
    for (int ni = 0; ni < 8; ++ni) {
      bf8_t bgf = *reinterpret_cast<const bf8_t*>(Wgb + (col0 + ni * 16) * 256 + kcol);
      acc[0][ni] = mfma16(s0, bgf, acc[0][ni]);
      acc[1][ni] = mfma16(s1, bgf, acc[1][ni]);
      bf8_t bdf = *reinterpret_cast<const bf8_t*>(Wdb + (col0 + ni * 16) * 256 + kcol);
      acc[0][ni] = mfma16(x0, bdf, acc[0][ni]);
      acc[1][ni] = mfma16(x1, bdf, acc[1][ni]);
    }
  }

#pragma unroll
  for (int ni = 0; ni < 8; ++ni) {
    int col = col0 + ni * 16;
    float bsum = bg[col] + bd[col];
    float mu = rmean[col];
    float rstd = rsqrtf(rvar[col] + 1e-5f);
    float ga = gamma[col], bt = beta[col];
#pragma unroll
    for (int mi = 0; mi < 2; ++mi)
#pragma unroll
      for (int r = 0; r < 4; ++r) {
        int row = wr * 32 + mi * 16 + l4 * 4 + r;
        float y = acc[mi][ni][r] + bsum;
        y = (y - mu) * rstd * ga + bt;
        float g = 0.5f * y * (1.f + erff(y * 0.70710678118654752f));
        float xv = bf2f(lds_x[row * 256 + (col ^ ((row & 7) << 3))]);
        out_blk[row * 256 + col] = g + xv;
      }
  }
}

extern "C" void kernel_launch(void* const* d_in, const int* in_sizes, int n_in,
                              void* d_out, int out_size, void* d_ws, size_t ws_size,
                              hipStream_t stream) {
  const float* xe    = (const float*)d_in[0];
  const float* Wp    = (const float*)d_in[1];
  const float* bp    = (const float*)d_in[2];
  const float* ap    = (const float*)d_in[3];
  const float* Wb    = (const float*)d_in[4];
  const float* bb    = (const float*)d_in[5];
  const float* Wg    = (const float*)d_in[6];
  const float* bg    = (const float*)d_in[7];
  const float* Wd    = (const float*)d_in[8];
  const float* bd    = (const float*)d_in[9];
  const float* gamma = (const float*)d_in[10];
  const float* beta  = (const float*)d_in[11];
  const float* rmean = (const float*)d_in[12];
  const float* rvar  = (const float*)d_in[13];
  float* out = (float*)d_out;

  short* wgt = (short*)d_ws;                       // 458752 B bf16 weights
  const size_t XG_OFF = 458752;                    // x bf16: 64 MiB
  const size_t US_OFF = XG_OFF + (size_t)MROWS * C * 2;
  const size_t NEED = US_OFF + (size_t)MROWS * C * 2;

  prep_weights<<<256, 256, 0, stream>>>(Wp, Wb, Wg, Wd, wgt);

  if (ws_size >= NEED) {
    short* xg = (short*)((char*)d_ws + XG_OFF);
    short* uS = (short*)((char*)d_ws + US_OFF);
    k1_proj<<<MROWS / 64, 256, 0, stream>>>(xe, wgt, bp, bb, xg, uS);
    k2_scan<<<NBE, 256, 0, stream>>>(ap, uS);
    k3_nolds<<<MROWS / 32, 256, 0, stream>>>(wgt, xg, uS, bg, bd, gamma, beta,
                                             rmean, rvar, out);
  } else {
    fused_fallback<<<NBE, 512, 0, stream>>>(xe, wgt, bp, ap, bb, bg, bd, gamma,
                                            beta, rmean, rvar, out);
  }
}

// Round 14
// 330.092 us; speedup vs baseline: 1.2120x; 1.1272x over previous
//
#include <hip/hip_runtime.h>
#include <hip/hip_bf16.h>

#define T 128
#define CIN 128
#define C 256
#define NBE 1024            // B*E
#define MROWS (NBE * T)     // 131072 total rows

typedef short bf8_t __attribute__((ext_vector_type(8)));
typedef short s4_t __attribute__((ext_vector_type(4)));
typedef float f4_t __attribute__((ext_vector_type(4)));

__device__ inline short f2bf(float f) {
  union { float f; unsigned u; } v; v.f = f;
  unsigned r = v.u + 0x7FFFu + ((v.u >> 16) & 1u);
  return (short)(r >> 16);
}
__device__ inline float bf2f(short s) {
  union { unsigned u; float f; } v; v.u = ((unsigned)(unsigned short)s) << 16;
  return v.f;
}
__device__ inline f4_t mfma16(bf8_t a, bf8_t b, f4_t c) {
  return __builtin_amdgcn_mfma_f32_16x16x32_bf16(a, b, c, 0, 0, 0);
}
// LDS bf16 frag load, XOR-swizzled rows: short index col ^ ((row&7)<<3).
__device__ inline bf8_t lds_frag(const short* base, int row, int kcol, int rowc) {
  return *reinterpret_cast<const bf8_t*>(base + row * rowc + (kcol ^ ((row & 7) << 3)));
}

__global__ void prep_weights(const float* __restrict__ Wp, const float* __restrict__ Wb,
                             const float* __restrict__ Wg, const float* __restrict__ Wd,
                             short* __restrict__ ws) {
  int i = blockIdx.x * 256 + threadIdx.x;  // grid 256*256 = 65536
  if (i < 32768) ws[i] = f2bf(Wp[i]);      // Wp [256][128]
  ws[32768 + i]  = f2bf(Wb[i]);            // Wb [256][256]
  ws[98304 + i]  = f2bf(Wg[i]);
  ws[163840 + i] = f2bf(Wd[i]);
}

// ======================= K1: x = xe@Wp^T+bp ; u = x@Wb^T+bb ==============
// grid 2048 (64-row tiles), 256 thr. LDS 48KB -> 3 blocks/CU.
__global__ __launch_bounds__(256, 1) void k1_proj(
    const float* __restrict__ xe, const short* __restrict__ wgt,
    const float* __restrict__ bp, const float* __restrict__ bb,
    short* __restrict__ xg, short* __restrict__ uS) {
  __shared__ __align__(16) short xe_s[64 * 128];  // 16KB
  __shared__ __align__(16) short x_s[64 * 256];   // 32KB (x, later u)

  const int tid = threadIdx.x;
  const int lane = tid & 63;
  const int w = tid >> 6;   // 0..3
  const int wr = w >> 1;    // 0..1: rows [wr*32, +32)
  const int wcg = w & 1;    // 0..1: cols [wcg*128, +128)
  const int l15 = lane & 15;
  const int l4 = lane >> 4;
  const int row0 = blockIdx.x * 64;

  const short* Wpb = wgt;          // [256][128]
  const short* Wbb = wgt + 32768;  // [256][256]

  // stage xe tile [64][128] fp32 -> bf16 swizzled
  {
    const float4* xe4 = reinterpret_cast<const float4*>(xe + (size_t)row0 * CIN);
#pragma unroll
    for (int j = 0; j < 8; ++j) {
      float4 v = xe4[j * 256 + tid];
      int fi = (j * 256 + tid) * 4;
      int r = fi >> 7, c = fi & 127;
      s4_t p = {f2bf(v.x), f2bf(v.y), f2bf(v.z), f2bf(v.w)};
      *reinterpret_cast<s4_t*>(&xe_s[r * 128 + (c ^ ((r & 7) << 3))]) = p;
    }
  }
  __syncthreads();

  const int row_a0 = wr * 32 + l15;
  const int colbase = wcg * 128 + l15;

  f4_t acc[2][8];
#pragma unroll
  for (int mi = 0; mi < 2; ++mi)
#pragma unroll
    for (int ni = 0; ni < 8; ++ni) acc[mi][ni] = (f4_t)(0.f);

  // GEMM1 (K=128)
#pragma unroll
  for (int kk = 0; kk < 4; ++kk) {
    int kcol = kk * 32 + l4 * 8;
    bf8_t a0 = lds_frag(xe_s, row_a0, kcol, 128);
    bf8_t a1 = lds_frag(xe_s, row_a0 + 16, kcol, 128);
#pragma unroll
    for (int ni = 0; ni < 8; ++ni) {
      bf8_t b = *reinterpret_cast<const bf8_t*>(Wpb + (colbase + ni * 16) * 128 + kcol);
      acc[0][ni] = mfma16(a0, b, acc[0][ni]);
      acc[1][ni] = mfma16(a1, b, acc[1][ni]);
    }
  }
  // x (+bp) -> x_s swizzled
#pragma unroll
  for (int ni = 0; ni < 8; ++ni) {
    int col = colbase + ni * 16;
    float bias = bp[col];
#pragma unroll
    for (int mi = 0; mi < 2; ++mi)
#pragma unroll
      for (int r = 0; r < 4; ++r) {
        int row = wr * 32 + mi * 16 + l4 * 4 + r;
        x_s[row * 256 + (col ^ ((row & 7) << 3))] = f2bf(acc[mi][ni][r] + bias);
      }
  }
  __syncthreads();

  // GEMM2 (K=256): acc = u (kept in regs across the xg store)
#pragma unroll
  for (int mi = 0; mi < 2; ++mi)
#pragma unroll
    for (int ni = 0; ni < 8; ++ni) acc[mi][ni] = (f4_t)(0.f);
#pragma unroll
  for (int kk = 0; kk < 8; ++kk) {
    int kcol = kk * 32 + l4 * 8;
    bf8_t a0 = lds_frag(x_s, row_a0, kcol, 256);
    bf8_t a1 = lds_frag(x_s, row_a0 + 16, kcol, 256);
#pragma unroll
    for (int ni = 0; ni < 8; ++ni) {
      bf8_t b = *reinterpret_cast<const bf8_t*>(Wbb + (colbase + ni * 16) * 256 + kcol);
      acc[0][ni] = mfma16(a0, b, acc[0][ni]);
      acc[1][ni] = mfma16(a1, b, acc[1][ni]);
    }
  }
  // x_s -> xg coalesced (bf16x8)
#pragma unroll
  for (int j = 0; j < 8; ++j) {
    int chunk = j * 256 + tid;          // 2048 chunks = 64 rows * 32
    int r = chunk >> 5, c8 = chunk & 31;
    bf8_t v = *reinterpret_cast<const bf8_t*>(&x_s[r * 256 + ((c8 * 8) ^ ((r & 7) << 3))]);
    *reinterpret_cast<bf8_t*>(&xg[(size_t)(row0 + r) * 256 + c8 * 8]) = v;
  }
  __syncthreads();  // x_s dead -> reuse for u staging

  // u (+bb) -> x_s swizzled, then coalesced store to uS
#pragma unroll
  for (int ni = 0; ni < 8; ++ni) {
    int col = colbase + ni * 16;
    float bias = bb[col];
#pragma unroll
    for (int mi = 0; mi < 2; ++mi)
#pragma unroll
      for (int r = 0; r < 4; ++r) {
        int row = wr * 32 + mi * 16 + l4 * 4 + r;
        x_s[row * 256 + (col ^ ((row & 7) << 3))] = f2bf(acc[mi][ni][r] + bias);
      }
  }
  __syncthreads();
#pragma unroll
  for (int j = 0; j < 8; ++j) {
    int chunk = j * 256 + tid;
    int r = chunk >> 5, c8 = chunk & 31;
    bf8_t v = *reinterpret_cast<const bf8_t*>(&x_s[r * 256 + ((c8 * 8) ^ ((r & 7) << 3))]);
    *reinterpret_cast<bf8_t*>(&uS[(size_t)(row0 + r) * 256 + c8 * 8]) = v;
  }
}

// ======================= K2: in-place scan u -> S ========================
__global__ __launch_bounds__(256, 1) void k2_scan(
    const float* __restrict__ ap, short* __restrict__ uS) {
  const int be = blockIdx.x;
  const int c = threadIdx.x;
  short* p = uS + (size_t)be * T * C + c;
  float a = tanhf(ap[c]);
  float un[4];
#pragma unroll
  for (int j = 0; j < 4; ++j) un[j] = bf2f(p[j * C]);
  float s = 0.f;
#pragma unroll 4
  for (int t = 0; t < T; ++t) {
    float nx = (t + 4 < T) ? bf2f(p[(t + 4) * C]) : 0.f;
    s = a * s + un[0];
    p[t * C] = f2bf(s);
    un[0] = un[1]; un[1] = un[2]; un[2] = un[3]; un[3] = nx;
  }
}

// ====== K3 (k1-style tile): y = S@Wg^T + x@Wd^T; BN; GELU; +x ============
// r13 post-mortem: no-LDS k3 (VGPR=64, 45% occ) still latency-naked per kk
// (MfmaUtil 5.8%): no reg headroom to prefetch 12 global loads/kk. k1's
// structure (LDS-staged A, small LDS, multi-block/CU) is the session's
// proven-efficient GEMM (~300 TF effective). Clone it: 32-row tiles, 32KB
// LDS (S+x swizzled) -> 5 blocks/CU by LDS; A-frags from LDS; out tile
// restaged in the same 32KB for coalesced float4 stores.
__global__ __launch_bounds__(256, 1) void k3_tile32(
    const short* __restrict__ wgt, const short* __restrict__ xg,
    const short* __restrict__ uS, const float* __restrict__ bg,
    const float* __restrict__ bd, const float* __restrict__ gamma,
    const float* __restrict__ beta, const float* __restrict__ rmean,
    const float* __restrict__ rvar, float* __restrict__ out) {
  __shared__ __align__(16) short lds[2][32 * 256];  // [0]=S, [1]=x; 32KB
  float* fbuf = reinterpret_cast<float*>(lds);      // 8192 fp32 = 32x256

  const int tid = threadIdx.x;
  const int lane = tid & 63;
  const int w = tid >> 6;          // 0..3: col group [w*64, +64)
  const int l15 = lane & 15;
  const int l4 = lane >> 4;        // 0..3
  const int row0 = blockIdx.x * 32;

  const short* Wgb = wgt + 98304;   // [256][256]
  const short* Wdb = wgt + 163840;  // [256][256]
  const int colbase = w * 64 + l15;

  // stage S and x tiles (coalesced bf16x8 -> swizzled LDS); 1024 chunks ea.
#pragma unroll
  for (int j = 0; j < 4; ++j) {
    int chunk = j * 256 + tid;       // 32 rows * 32 chunks
    int r = chunk >> 5, c8 = chunk & 31;
    int loff = r * 256 + ((c8 * 8) ^ ((r & 7) << 3));
    size_t goff = (size_t)(row0 + r) * 256 + c8 * 8;
    *reinterpret_cast<bf8_t*>(&lds[0][loff]) =
        *reinterpret_cast<const bf8_t*>(&uS[goff]);
    *reinterpret_cast<bf8_t*>(&lds[1][loff]) =
        *reinterpret_cast<const bf8_t*>(&xg[goff]);
  }
  __syncthreads();

  f4_t acc[2][4];
#pragma unroll
  for (int mi = 0; mi < 2; ++mi)
#pragma unroll
    for (int ni = 0; ni < 4; ++ni) acc[mi][ni] = (f4_t)(0.f);

#pragma unroll
  for (int kk = 0; kk < 8; ++kk) {
    const int kcol = kk * 32 + l4 * 8;
    bf8_t s0 = lds_frag(lds[0], l15, kcol, 256);
    bf8_t s1 = lds_frag(lds[0], l15 + 16, kcol, 256);
#pragma unroll
    for (int ni = 0; ni < 4; ++ni) {
      bf8_t bgf = *reinterpret_cast<const bf8_t*>(Wgb + (colbase + ni * 16) * 256 + kcol);
      acc[0][ni] = mfma16(s0, bgf, acc[0][ni]);
      acc[1][ni] = mfma16(s1, bgf, acc[1][ni]);
    }
    bf8_t x0 = lds_frag(lds[1], l15, kcol, 256);
    bf8_t x1 = lds_frag(lds[1], l15 + 16, kcol, 256);
#pragma unroll
    for (int ni = 0; ni < 4; ++ni) {
      bf8_t bdf = *reinterpret_cast<const bf8_t*>(Wdb + (colbase + ni * 16) * 256 + kcol);
      acc[0][ni] = mfma16(x0, bdf, acc[0][ni]);
      acc[1][ni] = mfma16(x1, bdf, acc[1][ni]);
    }
  }

  // epilogue: +bg+bd, BN(eval), exact GELU, +x (residual from lds[1])
#pragma unroll
  for (int ni = 0; ni < 4; ++ni) {
    const int col = colbase + ni * 16;
    float bsum = bg[col] + bd[col];
    float mu = rmean[col];
    float rstd = rsqrtf(rvar[col] + 1e-5f);
    float ga = gamma[col], bt = beta[col];
#pragma unroll
    for (int mi = 0; mi < 2; ++mi)
#pragma unroll
      for (int r = 0; r < 4; ++r) {
        int row = mi * 16 + l4 * 4 + r;   // 0..31 within tile
        float y = acc[mi][ni][r] + bsum;
        y = (y - mu) * rstd * ga + bt;
        float g = 0.5f * y * (1.f + erff(y * 0.70710678118654752f));
        float xv = bf2f(lds[1][row * 256 + (col ^ ((row & 7) << 3))]);
        acc[mi][ni][r] = g + xv;
      }
  }
  __syncthreads();  // all LDS reads done -> reuse as fp32 out tile

  // stage fp32 out (swizzle col ^ (l4<<4); (row>>2)&3 == l4 here)
#pragma unroll
  for (int ni = 0; ni < 4; ++ni) {
    const int col = colbase + ni * 16;
#pragma unroll
    for (int mi = 0; mi < 2; ++mi)
#pragma unroll
      for (int r = 0; r < 4; ++r) {
        int row = mi * 16 + l4 * 4 + r;
        fbuf[row * 256 + (col ^ (l4 << 4))] = acc[mi][ni][r];
      }
  }
  __syncthreads();

  // coalesced float4 out: 32x256 fp32 = 2048 float4, 256 thr -> j<8
  float4* out4 = reinterpret_cast<float4*>(out + (size_t)row0 * 256);
#pragma unroll
  for (int j = 0; j < 8; ++j) {
    int f4i = j * 256 + tid;
    int row = f4i >> 6;
    int c4 = (f4i & 63) << 2;
    int sc = c4 ^ (((row >> 2) & 3) << 4);
    out4[f4i] = *reinterpret_cast<float4*>(&fbuf[row * 256 + sc]);
  }
}

// =============== fallback: round-1 proven fused kernel (298us) ===========
__global__ __launch_bounds__(512, 1) void fused_fallback(
    const float* __restrict__ xe, const short* __restrict__ wgt,
    const float* __restrict__ bp, const float* __restrict__ a_param,
    const float* __restrict__ bb, const float* __restrict__ bg,
    const float* __restrict__ bd, const float* __restrict__ gamma,
    const float* __restrict__ beta, const float* __restrict__ rmean,
    const float* __restrict__ rvar, float* __restrict__ out) {
  __shared__ __align__(16) short lds_x[T * C];
  __shared__ __align__(16) short lds_u[T * C];
  short* lds_xe = lds_u;

  const int tid = threadIdx.x;
  const int lane = tid & 63;
  const int w = tid >> 6;
  const int wr = w >> 1;
  const int wc = w & 1;
  const int l15 = lane & 15;
  const int l4 = lane >> 4;
  const int be = blockIdx.x;

  const float* xe_blk = xe + (size_t)be * T * CIN;
  float* out_blk = out + (size_t)be * T * C;

  const short* Wpb = wgt;
  const short* Wbb = wgt + 32768;
  const short* Wgb = wgt + 98304;
  const short* Wdb = wgt + 163840;

#pragma unroll
  for (int j = 0; j < 32; ++j) {
    int idx = j * 512 + tid;
    int r = idx >> 7, c = idx & 127;
    lds_xe[r * 128 + (c ^ ((r & 7) << 3))] = f2bf(xe_blk[idx]);
  }
  __syncthreads();

  const int row_a0 = wr * 32 + l15;
  const int col0 = wc * 128 + l15;
  f4_t acc[2][8];

#pragma unroll
  for (int mi = 0; mi < 2; ++mi)
#pragma unroll
    for (int ni = 0; ni < 8; ++ni) acc[mi][ni] = (f4_t)(0.f);
#pragma unroll
  for (int kk = 0; kk < 4; ++kk) {
    int kcol = kk * 32 + l4 * 8;
    bf8_t a0 = lds_frag(lds_xe, row_a0, kcol, 128);
    bf8_t a1 = lds_frag(lds_xe, row_a0 + 16, kcol, 128);
#pragma unroll
    for (int ni = 0; ni < 8; ++ni) {
      bf8_t b = *reinterpret_cast<const bf8_t*>(Wpb + (col0 + ni * 16) * 128 + kcol);
      acc[0][ni] = mfma16(a0, b, acc[0][ni]);
      acc[1][ni] = mfma16(a1, b, acc[1][ni]);
    }
  }
#pragma unroll
  for (int ni = 0; ni < 8; ++ni) {
    int col = col0 + ni * 16;
    float bias = bp[col];
#pragma unroll
    for (int mi = 0; mi < 2; ++mi)
#pragma unroll
      for (int r = 0; r < 4; ++r) {
        int row = wr * 32 + mi * 16 + l4 * 4 + r;
        lds_x[row * 256 + (col ^ ((row & 7) << 3))] = f2bf(acc[mi][ni][r] + bias);
      }
  }
  __syncthreads();

#pragma unroll
  for (int mi = 0; mi < 2; ++mi)
#pragma unroll
    for (int ni = 0; ni < 8; ++ni) acc[mi][ni] = (f4_t)(0.f);
#pragma unroll
  for (int kk = 0; kk < 8; ++kk) {
    int kcol = kk * 32 + l4 * 8;
    bf8_t a0 = lds_frag(lds_x, row_a0, kcol, 256);
    bf8_t a1 = lds_frag(lds_x, row_a0 + 16, kcol, 256);
#pragma unroll
    for (int ni = 0; ni < 8; ++ni) {
      bf8_t b = *reinterpret_cast<const bf8_t*>(Wbb + (col0 + ni * 16) * 256 + kcol);
      acc[0][ni] = mfma16(a0, b, acc[0][ni]);
      acc[1][ni] = mfma16(a1, b, acc[1][ni]);
    }
  }
#pragma unroll
  for (int ni = 0; ni < 8; ++ni) {
    int col = col0 + ni * 16;
    float bias = bb[col];
#pragma unroll
    for (int mi = 0; mi < 2; ++mi)
#pragma unroll
      for (int r = 0; r < 4; ++r) {
        int row = wr * 32 + mi * 16 + l4 * 4 + r;
        lds_u[row * 256 + (col ^ ((row & 7) << 3))] = f2bf(acc[mi][ni][r] + bias);
      }
  }
  __syncthreads();

  if (tid < 256) {
    float a = tanhf(a_param[tid]);
    float s = 0.f;
    float un = bf2f(lds_u[tid]);
#pragma unroll 8
    for (int t = 0; t < 128; ++t) {
      float unn = (t < 127) ? bf2f(lds_u[(t + 1) * 256 + (tid ^ (((t + 1) & 7) << 3))]) : 0.f;
      s = a * s + un;
      lds_u[t * 256 + (tid ^ ((t & 7) << 3))] = f2bf(s);
      un = unn;
    }
  }
  __syncthreads();

#pragma unroll
  for (int mi = 0; mi < 2; ++mi)
#pragma unroll
    for (int ni = 0; ni < 8; ++ni) acc[mi][ni] = (f4_t)(0.f);
#pragma unroll
  for (int kk = 0; kk < 8; ++kk) {
    int kcol = kk * 32 + l4 * 8;
    bf8_t s0 = lds_frag(lds_u, row_a0, kcol, 256);
    bf8_t s1 = lds_frag(lds_u, row_a0 + 16, kcol, 256);
    bf8_t x0 = lds_frag(lds_x, row_a0, kcol, 256);
    bf8_t x1 = lds_frag(lds_x, row_a0 + 16, kcol, 256);
#pragma unroll
    for (int ni = 0; ni < 8; ++ni) {
      bf8_t bgf = *reinterpret_cast<const bf8_t*>(Wgb + (col0 + ni * 16) * 256 + kcol);
      acc[0][ni] = mfma16(s0, bgf, acc[0][ni]);
      acc[1][ni] = mfma16(s1, bgf, acc[1][ni]);
      bf8_t bdf = *reinterpret_cast<const bf8_t*>(Wdb + (col0 + ni * 16) * 256 + kcol);
      acc[0][ni] = mfma16(x0, bdf, acc[0][ni]);
      acc[1][ni] = mfma16(x1, bdf, acc[1][ni]);
    }
  }

#pragma unroll
  for (int ni = 0; ni < 8; ++ni) {
    int col = col0 + ni * 16;
    float bsum = bg[col] + bd[col];
    float mu = rmean[col];
    float rstd = rsqrtf(rvar[col] + 1e-5f);
    float ga = gamma[col], bt = beta[col];
#pragma unroll
    for (int mi = 0; mi < 2; ++mi)
#pragma unroll
      for (int r = 0; r < 4; ++r) {
        int row = wr * 32 + mi * 16 + l4 * 4 + r;
        float y = acc[mi][ni][r] + bsum;
        y = (y - mu) * rstd * ga + bt;
        float g = 0.5f * y * (1.f + erff(y * 0.70710678118654752f));
        float xv = bf2f(lds_x[row * 256 + (col ^ ((row & 7) << 3))]);
        out_blk[row * 256 + col] = g + xv;
      }
  }
}

extern "C" void kernel_launch(void* const* d_in, const int* in_sizes, int n_in,
                              void* d_out, int out_size, void* d_ws, size_t ws_size,
                              hipStream_t stream) {
  const float* xe    = (const float*)d_in[0];
  const float* Wp    = (const float*)d_in[1];
  const float* bp    = (const float*)d_in[2];
  const float* ap    = (const float*)d_in[3];
  const float* Wb    = (const float*)d_in[4];
  const float* bb    = (const float*)d_in[5];
  const float* Wg    = (const float*)d_in[6];
  const float* bg    = (const float*)d_in[7];
  const float* Wd    = (const float*)d_in[8];
  const float* bd    = (const float*)d_in[9];
  const float* gamma = (const float*)d_in[10];
  const float* beta  = (const float*)d_in[11];
  const float* rmean = (const float*)d_in[12];
  const float* rvar  = (const float*)d_in[13];
  float* out = (float*)d_out;

  short* wgt = (short*)d_ws;                       // 458752 B bf16 weights
  const size_t XG_OFF = 458752;                    // x bf16: 64 MiB
  const size_t US_OFF = XG_OFF + (size_t)MROWS * C * 2;
  const size_t NEED = US_OFF + (size_t)MROWS * C * 2;

  prep_weights<<<256, 256, 0, stream>>>(Wp, Wb, Wg, Wd, wgt);

  if (ws_size >= NEED) {
    short* xg = (short*)((char*)d_ws + XG_OFF);
    short* uS = (short*)((char*)d_ws + US_OFF);
    k1_proj<<<MROWS / 64, 256, 0, stream>>>(xe, wgt, bp, bb, xg, uS);
    k2_scan<<<NBE, 256, 0, stream>>>(ap, uS);
    k3_tile32<<<MROWS / 32, 256, 0, stream>>>(wgt, xg, uS, bg, bd, gamma, beta,
                                              rmean, rvar, out);
  } else {
    fused_fallback<<<NBE, 512, 0, stream>>>(xe, wgt, bp, ap, bb, bg, bd, gamma,
                                            beta, rmean, rvar, out);
  }
}

// Round 15
// 321.714 us; speedup vs baseline: 1.2436x; 1.0260x over previous
//
#include <hip/hip_runtime.h>
#include <hip/hip_bf16.h>

#define T 128
#define CIN 128
#define C 256
#define NBE 1024            // B*E
#define MROWS (NBE * T)     // 131072 total rows

typedef short bf8_t __attribute__((ext_vector_type(8)));
typedef short s4_t __attribute__((ext_vector_type(4)));
typedef float f4_t __attribute__((ext_vector_type(4)));

__device__ inline short f2bf(float f) {
  union { float f; unsigned u; } v; v.f = f;
  unsigned r = v.u + 0x7FFFu + ((v.u >> 16) & 1u);
  return (short)(r >> 16);
}
__device__ inline float bf2f(short s) {
  union { unsigned u; float f; } v; v.u = ((unsigned)(unsigned short)s) << 16;
  return v.f;
}
__device__ inline f4_t mfma16(bf8_t a, bf8_t b, f4_t c) {
  return __builtin_amdgcn_mfma_f32_16x16x32_bf16(a, b, c, 0, 0, 0);
}
// LDS bf16 frag load, XOR-swizzled rows: short index col ^ ((row&7)<<3).
__device__ inline bf8_t lds_frag(const short* base, int row, int kcol, int rowc) {
  return *reinterpret_cast<const bf8_t*>(base + row * rowc + (kcol ^ ((row & 7) << 3)));
}

__global__ void prep_weights(const float* __restrict__ Wp, const float* __restrict__ Wb,
                             const float* __restrict__ Wg, const float* __restrict__ Wd,
                             short* __restrict__ ws) {
  int i = blockIdx.x * 256 + threadIdx.x;  // grid 256*256 = 65536
  if (i < 32768) ws[i] = f2bf(Wp[i]);      // Wp [256][128]
  ws[32768 + i]  = f2bf(Wb[i]);            // Wb [256][256]
  ws[98304 + i]  = f2bf(Wg[i]);
  ws[163840 + i] = f2bf(Wd[i]);
}

// ======================= K1: x = xe@Wp^T+bp ; u = x@Wb^T+bb ==============
// grid 2048 (64-row tiles), 256 thr. LDS 48KB -> 3 blocks/CU.
__global__ __launch_bounds__(256, 1) void k1_proj(
    const float* __restrict__ xe, const short* __restrict__ wgt,
    const float* __restrict__ bp, const float* __restrict__ bb,
    short* __restrict__ xg, short* __restrict__ uS) {
  __shared__ __align__(16) short xe_s[64 * 128];  // 16KB
  __shared__ __align__(16) short x_s[64 * 256];   // 32KB (x, later u)

  const int tid = threadIdx.x;
  const int lane = tid & 63;
  const int w = tid >> 6;   // 0..3
  const int wr = w >> 1;    // 0..1: rows [wr*32, +32)
  const int wcg = w & 1;    // 0..1: cols [wcg*128, +128)
  const int l15 = lane & 15;
  const int l4 = lane >> 4;
  const int row0 = blockIdx.x * 64;

  const short* Wpb = wgt;          // [256][128]
  const short* Wbb = wgt + 32768;  // [256][256]

  // stage xe tile [64][128] fp32 -> bf16 swizzled
  {
    const float4* xe4 = reinterpret_cast<const float4*>(xe + (size_t)row0 * CIN);
#pragma unroll
    for (int j = 0; j < 8; ++j) {
      float4 v = xe4[j * 256 + tid];
      int fi = (j * 256 + tid) * 4;
      int r = fi >> 7, c = fi & 127;
      s4_t p = {f2bf(v.x), f2bf(v.y), f2bf(v.z), f2bf(v.w)};
      *reinterpret_cast<s4_t*>(&xe_s[r * 128 + (c ^ ((r & 7) << 3))]) = p;
    }
  }
  __syncthreads();

  const int row_a0 = wr * 32 + l15;
  const int colbase = wcg * 128 + l15;

  f4_t acc[2][8];
#pragma unroll
  for (int mi = 0; mi < 2; ++mi)
#pragma unroll
    for (int ni = 0; ni < 8; ++ni) acc[mi][ni] = (f4_t)(0.f);

  // GEMM1 (K=128)
#pragma unroll
  for (int kk = 0; kk < 4; ++kk) {
    int kcol = kk * 32 + l4 * 8;
    bf8_t a0 = lds_frag(xe_s, row_a0, kcol, 128);
    bf8_t a1 = lds_frag(xe_s, row_a0 + 16, kcol, 128);
#pragma unroll
    for (int ni = 0; ni < 8; ++ni) {
      bf8_t b = *reinterpret_cast<const bf8_t*>(Wpb + (colbase + ni * 16) * 128 + kcol);
      acc[0][ni] = mfma16(a0, b, acc[0][ni]);
      acc[1][ni] = mfma16(a1, b, acc[1][ni]);
    }
  }
  // x (+bp) -> x_s swizzled
#pragma unroll
  for (int ni = 0; ni < 8; ++ni) {
    int col = colbase + ni * 16;
    float bias = bp[col];
#pragma unroll
    for (int mi = 0; mi < 2; ++mi)
#pragma unroll
      for (int r = 0; r < 4; ++r) {
        int row = wr * 32 + mi * 16 + l4 * 4 + r;
        x_s[row * 256 + (col ^ ((row & 7) << 3))] = f2bf(acc[mi][ni][r] + bias);
      }
  }
  __syncthreads();

  // GEMM2 (K=256): acc = u (kept in regs across the xg store)
#pragma unroll
  for (int mi = 0; mi < 2; ++mi)
#pragma unroll
    for (int ni = 0; ni < 8; ++ni) acc[mi][ni] = (f4_t)(0.f);
#pragma unroll
  for (int kk = 0; kk < 8; ++kk) {
    int kcol = kk * 32 + l4 * 8;
    bf8_t a0 = lds_frag(x_s, row_a0, kcol, 256);
    bf8_t a1 = lds_frag(x_s, row_a0 + 16, kcol, 256);
#pragma unroll
    for (int ni = 0; ni < 8; ++ni) {
      bf8_t b = *reinterpret_cast<const bf8_t*>(Wbb + (colbase + ni * 16) * 256 + kcol);
      acc[0][ni] = mfma16(a0, b, acc[0][ni]);
      acc[1][ni] = mfma16(a1, b, acc[1][ni]);
    }
  }
  // x_s -> xg coalesced (bf16x8)
#pragma unroll
  for (int j = 0; j < 8; ++j) {
    int chunk = j * 256 + tid;          // 2048 chunks = 64 rows * 32
    int r = chunk >> 5, c8 = chunk & 31;
    bf8_t v = *reinterpret_cast<const bf8_t*>(&x_s[r * 256 + ((c8 * 8) ^ ((r & 7) << 3))]);
    *reinterpret_cast<bf8_t*>(&xg[(size_t)(row0 + r) * 256 + c8 * 8]) = v;
  }
  __syncthreads();  // x_s dead -> reuse for u staging

  // u (+bb) -> x_s swizzled, then coalesced store to uS
#pragma unroll
  for (int ni = 0; ni < 8; ++ni) {
    int col = colbase + ni * 16;
    float bias = bb[col];
#pragma unroll
    for (int mi = 0; mi < 2; ++mi)
#pragma unroll
      for (int r = 0; r < 4; ++r) {
        int row = wr * 32 + mi * 16 + l4 * 4 + r;
        x_s[row * 256 + (col ^ ((row & 7) << 3))] = f2bf(acc[mi][ni][r] + bias);
      }
  }
  __syncthreads();
#pragma unroll
  for (int j = 0; j < 8; ++j) {
    int chunk = j * 256 + tid;
    int r = chunk >> 5, c8 = chunk & 31;
    bf8_t v = *reinterpret_cast<const bf8_t*>(&x_s[r * 256 + ((c8 * 8) ^ ((r & 7) << 3))]);
    *reinterpret_cast<bf8_t*>(&uS[(size_t)(row0 + r) * 256 + c8 * 8]) = v;
  }
}

// ======================= K2: in-place scan u -> S ========================
__global__ __launch_bounds__(256, 1) void k2_scan(
    const float* __restrict__ ap, short* __restrict__ uS) {
  const int be = blockIdx.x;
  const int c = threadIdx.x;
  short* p = uS + (size_t)be * T * C + c;
  float a = tanhf(ap[c]);
  float un[4];
#pragma unroll
  for (int j = 0; j < 4; ++j) un[j] = bf2f(p[j * C]);
  float s = 0.f;
#pragma unroll 4
  for (int t = 0; t < T; ++t) {
    float nx = (t + 4 < T) ? bf2f(p[(t + 4) * C]) : 0.f;
    s = a * s + un[0];
    p[t * C] = f2bf(s);
    un[0] = un[1]; un[1] = un[2]; un[2] = un[3]; un[3] = nx;
  }
}

// ====== K3 v3 (64 rows/wave): y = S@Wg^T + x@Wd^T; BN; GELU; +x ==========
// r14 post-mortem: Mw=32 rows/wave -> each B-frag feeds only 2 MFMAs; 4096
// blocks x 256KB = 1GB of latency-exposed L2 B-loads; MfmaUtil 7%.
// This version: 64-row blocks (grid 2048), 4 waves x (64 rows x 64 cols).
// Per kk: 8 LDS A-reads + 8 B-loads + 32 MFMAs (~620 cyc) -> B-reuse 4,
// B-traffic halved, per-kk compute deep enough to hide unrolled loads.
// LDS 64KB (S+x swizzled) -> 2 blocks/CU (same occupancy as r14: isolates
// the reuse/density variable). Out restaged in same LDS, coalesced float4.
__global__ __launch_bounds__(256, 1) void k3_tile64(
    const short* __restrict__ wgt, const short* __restrict__ xg,
    const short* __restrict__ uS, const float* __restrict__ bg,
    const float* __restrict__ bd, const float* __restrict__ gamma,
    const float* __restrict__ beta, const float* __restrict__ rmean,
    const float* __restrict__ rvar, float* __restrict__ out) {
  __shared__ __align__(16) short lds[2][64 * 256];  // [0]=S, [1]=x; 64KB
  float* fbuf = reinterpret_cast<float*>(lds);      // 16384 fp32 = 64x256

  const int tid = threadIdx.x;
  const int lane = tid & 63;
  const int w = tid >> 6;          // 0..3: col group [w*64, +64)
  const int l15 = lane & 15;
  const int l4 = lane >> 4;        // 0..3
  const int row0 = blockIdx.x * 64;

  const short* Wgb = wgt + 98304;   // [256][256]
  const short* Wdb = wgt + 163840;  // [256][256]
  const int colbase = w * 64 + l15;

  // stage S and x tiles (coalesced bf16x8 -> swizzled LDS); 2048 chunks ea.
#pragma unroll
  for (int j = 0; j < 8; ++j) {
    int chunk = j * 256 + tid;       // 64 rows * 32 chunks
    int r = chunk >> 5, c8 = chunk & 31;
    int loff = r * 256 + ((c8 * 8) ^ ((r & 7) << 3));
    size_t goff = (size_t)(row0 + r) * 256 + c8 * 8;
    *reinterpret_cast<bf8_t*>(&lds[0][loff]) =
        *reinterpret_cast<const bf8_t*>(&uS[goff]);
    *reinterpret_cast<bf8_t*>(&lds[1][loff]) =
        *reinterpret_cast<const bf8_t*>(&xg[goff]);
  }
  __syncthreads();

  f4_t acc[4][4];  // [row-frag mi: rows mi*16+l4*4+r][col-frag ni]
#pragma unroll
  for (int mi = 0; mi < 4; ++mi)
#pragma unroll
    for (int ni = 0; ni < 4; ++ni) acc[mi][ni] = (f4_t)(0.f);

#pragma unroll
  for (int kk = 0; kk < 8; ++kk) {
    const int kcol = kk * 32 + l4 * 8;
    // S pass: 4 A-frags x 4 Wg-frags = 16 MFMAs
    bf8_t sa[4];
#pragma unroll
    for (int mi = 0; mi < 4; ++mi) sa[mi] = lds_frag(lds[0], l15 + mi * 16, kcol, 256);
#pragma unroll
    for (int ni = 0; ni < 4; ++ni) {
      bf8_t bgf = *reinterpret_cast<const bf8_t*>(Wgb + (colbase + ni * 16) * 256 + kcol);
#pragma unroll
      for (int mi = 0; mi < 4; ++mi) acc[mi][ni] = mfma16(sa[mi], bgf, acc[mi][ni]);
    }
    // x pass: 4 A-frags x 4 Wd-frags = 16 MFMAs
    bf8_t xa[4];
#pragma unroll
    for (int mi = 0; mi < 4; ++mi) xa[mi] = lds_frag(lds[1], l15 + mi * 16, kcol, 256);
#pragma unroll
    for (int ni = 0; ni < 4; ++ni) {
      bf8_t bdf = *reinterpret_cast<const bf8_t*>(Wdb + (colbase + ni * 16) * 256 + kcol);
#pragma unroll
      for (int mi = 0; mi < 4; ++mi) acc[mi][ni] = mfma16(xa[mi], bdf, acc[mi][ni]);
    }
  }

  // epilogue: +bg+bd, BN(eval), exact GELU, +x (residual from lds[1])
#pragma unroll
  for (int ni = 0; ni < 4; ++ni) {
    const int col = colbase + ni * 16;
    float bsum = bg[col] + bd[col];
    float mu = rmean[col];
    float rstd = rsqrtf(rvar[col] + 1e-5f);
    float ga = gamma[col], bt = beta[col];
#pragma unroll
    for (int mi = 0; mi < 4; ++mi)
#pragma unroll
      for (int r = 0; r < 4; ++r) {
        int row = mi * 16 + l4 * 4 + r;   // 0..63 within tile
        float y = acc[mi][ni][r] + bsum;
        y = (y - mu) * rstd * ga + bt;
        float g = 0.5f * y * (1.f + erff(y * 0.70710678118654752f));
        float xv = bf2f(lds[1][row * 256 + (col ^ ((row & 7) << 3))]);
        acc[mi][ni][r] = g + xv;
      }
  }
  __syncthreads();  // all LDS reads done -> reuse as fp32 out tile

  // stage fp32 out (swizzle col ^ (l4<<4); (row>>2)&3 == l4 for our rows)
#pragma unroll
  for (int ni = 0; ni < 4; ++ni) {
    const int col = colbase + ni * 16;
#pragma unroll
    for (int mi = 0; mi < 4; ++mi)
#pragma unroll
      for (int r = 0; r < 4; ++r) {
        int row = mi * 16 + l4 * 4 + r;
        fbuf[row * 256 + (col ^ (l4 << 4))] = acc[mi][ni][r];
      }
  }
  __syncthreads();

  // coalesced float4 out: 64x256 fp32 = 4096 float4, 256 thr -> j<16
  float4* out4 = reinterpret_cast<float4*>(out + (size_t)row0 * 256);
#pragma unroll
  for (int j = 0; j < 16; ++j) {
    int f4i = j * 256 + tid;
    int row = f4i >> 6;
    int c4 = (f4i & 63) << 2;
    int sc = c4 ^ (((row >> 2) & 3) << 4);
    out4[f4i] = *reinterpret_cast<float4*>(&fbuf[row * 256 + sc]);
  }
}

// =============== fallback: round-1 proven fused kernel (298us) ===========
__global__ __launch_bounds__(512, 1) void fused_fallback(
    const float* __restrict__ xe, const short* __restrict__ wgt,
    const float* __restrict__ bp, const float* __restrict__ a_param,
    const float* __restrict__ bb, const float* __restrict__ bg,
    const float* __restrict__ bd, const float* __restrict__ gamma,
    const float* __restrict__ beta, const float* __restrict__ rmean,
    const float* __restrict__ rvar, float* __restrict__ out) {
  __shared__ __align__(16) short lds_x[T * C];
  __shared__ __align__(16) short lds_u[T * C];
  short* lds_xe = lds_u;

  const int tid = threadIdx.x;
  const int lane = tid & 63;
  const int w = tid >> 6;
  const int wr = w >> 1;
  const int wc = w & 1;
  const int l15 = lane & 15;
  const int l4 = lane >> 4;
  const int be = blockIdx.x;

  const float* xe_blk = xe + (size_t)be * T * CIN;
  float* out_blk = out + (size_t)be * T * C;

  const short* Wpb = wgt;
  const short* Wbb = wgt + 32768;
  const short* Wgb = wgt + 98304;
  const short* Wdb = wgt + 163840;

#pragma unroll
  for (int j = 0; j < 32; ++j) {
    int idx = j * 512 + tid;
    int r = idx >> 7, c = idx & 127;
    lds_xe[r * 128 + (c ^ ((r & 7) << 3))] = f2bf(xe_blk[idx]);
  }
  __syncthreads();

  const int row_a0 = wr * 32 + l15;
  const int col0 = wc * 128 + l15;
  f4_t acc[2][8];

#pragma unroll
  for (int mi = 0; mi < 2; ++mi)
#pragma unroll
    for (int ni = 0; ni < 8; ++ni) acc[mi][ni] = (f4_t)(0.f);
#pragma unroll
  for (int kk = 0; kk < 4; ++kk) {
    int kcol = kk * 32 + l4 * 8;
    bf8_t a0 = lds_frag(lds_xe, row_a0, kcol, 128);
    bf8_t a1 = lds_frag(lds_xe, row_a0 + 16, kcol, 128);
#pragma unroll
    for (int ni = 0; ni < 8; ++ni) {
      bf8_t b = *reinterpret_cast<const bf8_t*>(Wpb + (col0 + ni * 16) * 128 + kcol);
      acc[0][ni] = mfma16(a0, b, acc[0][ni]);
      acc[1][ni] = mfma16(a1, b, acc[1][ni]);
    }
  }
#pragma unroll
  for (int ni = 0; ni < 8; ++ni) {
    int col = col0 + ni * 16;
    float bias = bp[col];
#pragma unroll
    for (int mi = 0; mi < 2; ++mi)
#pragma unroll
      for (int r = 0; r < 4; ++r) {
        int row = wr * 32 + mi * 16 + l4 * 4 + r;
        lds_x[row * 256 + (col ^ ((row & 7) << 3))] = f2bf(acc[mi][ni][r] + bias);
      }
  }
  __syncthreads();

#pragma unroll
  for (int mi = 0; mi < 2; ++mi)
#pragma unroll
    for (int ni = 0; ni < 8; ++ni) acc[mi][ni] = (f4_t)(0.f);
#pragma unroll
  for (int kk = 0; kk < 8; ++kk) {
    int kcol = kk * 32 + l4 * 8;
    bf8_t a0 = lds_frag(lds_x, row_a0, kcol, 256);
    bf8_t a1 = lds_frag(lds_x, row_a0 + 16, kcol, 256);
#pragma unroll
    for (int ni = 0; ni < 8; ++ni) {
      bf8_t b = *reinterpret_cast<const bf8_t*>(Wbb + (col0 + ni * 16) * 256 + kcol);
      acc[0][ni] = mfma16(a0, b, acc[0][ni]);
      acc[1][ni] = mfma16(a1, b, acc[1][ni]);
    }
  }
#pragma unroll
  for (int ni = 0; ni < 8; ++ni) {
    int col = col0 + ni * 16;
    float bias = bb[col];
#pragma unroll
    for (int mi = 0; mi < 2; ++mi)
#pragma unroll
      for (int r = 0; r < 4; ++r) {
        int row = wr * 32 + mi * 16 + l4 * 4 + r;
        lds_u[row * 256 + (col ^ ((row & 7) << 3))] = f2bf(acc[mi][ni][r] + bias);
      }
  }
  __syncthreads();

  if (tid < 256) {
    float a = tanhf(a_param[tid]);
    float s = 0.f;
    float un = bf2f(lds_u[tid]);
#pragma unroll 8
    for (int t = 0; t < 128; ++t) {
      float unn = (t < 127) ? bf2f(lds_u[(t + 1) * 256 + (tid ^ (((t + 1) & 7) << 3))]) : 0.f;
      s = a * s + un;
      lds_u[t * 256 + (tid ^ ((t & 7) << 3))] = f2bf(s);
      un = unn;
    }
  }
  __syncthreads();

#pragma unroll
  for (int mi = 0; mi < 2; ++mi)
#pragma unroll
    for (int ni = 0; ni < 8; ++ni) acc[mi][ni] = (f4_t)(0.f);
#pragma unroll
  for (int kk = 0; kk < 8; ++kk) {
    int kcol = kk * 32 + l4 * 8;
    bf8_t s0 = lds_frag(lds_u, row_a0, kcol, 256);
    bf8_t s1 = lds_frag(lds_u, row_a0 + 16, kcol, 256);
    bf8_t x0 = lds_frag(lds_x, row_a0, kcol, 256);
    bf8_t x1 = lds_frag(lds_x, row_a0 + 16, kcol, 256);
#pragma unroll
    for (int ni = 0; ni < 8; ++ni) {
      bf8_t bgf = *reinterpret_cast<const bf8_t*>(Wgb + (col0 + ni * 16) * 256 + kcol);
      acc[0][ni] = mfma16(s0, bgf, acc[0][ni]);
      acc[1][ni] = mfma16(s1, bgf, acc[1][ni]);
      bf8_t bdf = *reinterpret_cast<const bf8_t*>(Wdb + (col0 + ni * 16) * 256 + kcol);
      acc[0][ni] = mfma16(x0, bdf, acc[0][ni]);
      acc[1][ni] = mfma16(x1, bdf, acc[1][ni]);
    }
  }

#pragma unroll
  for (int ni = 0; ni < 8; ++ni) {
    int col = col0 + ni * 16;
    float bsum = bg[col] + bd[col];
    float mu = rmean[col];
    float rstd = rsqrtf(rvar[col] + 1e-5f);
    float ga = gamma[col], bt = beta[col];
#pragma unroll
    for (int mi = 0; mi < 2; ++mi)
#pragma unroll
      for (int r = 0; r < 4; ++r) {
        int row = wr * 32 + mi * 16 + l4 * 4 + r;
        float y = acc[mi][ni][r] + bsum;
        y = (y - mu) * rstd * ga + bt;
        float g = 0.5f * y * (1.f + erff(y * 0.70710678118654752f));
        float xv = bf2f(lds_x[row * 256 + (col ^ ((row & 7) << 3))]);
        out_blk[row * 256 + col] = g + xv;
      }
  }
}

extern "C" void kernel_launch(void* const* d_in, const int* in_sizes, int n_in,
                              void* d_out, int out_size, void* d_ws, size_t ws_size,
                              hipStream_t stream) {
  const float* xe    = (const float*)d_in[0];
  const float* Wp    = (const float*)d_in[1];
  const float* bp    = (const float*)d_in[2];
  const float* ap    = (const float*)d_in[3];
  const float* Wb    = (const float*)d_in[4];
  const float* bb    = (const float*)d_in[5];
  const float* Wg    = (const float*)d_in[6];
  const float* bg    = (const float*)d_in[7];
  const float* Wd    = (const float*)d_in[8];
  const float* bd    = (const float*)d_in[9];
  const float* gamma = (const float*)d_in[10];
  const float* beta  = (const float*)d_in[11];
  const float* rmean = (const float*)d_in[12];
  const float* rvar  = (const float*)d_in[13];
  float* out = (float*)d_out;

  short* wgt = (short*)d_ws;                       // 458752 B bf16 weights
  const size_t XG_OFF = 458752;                    // x bf16: 64 MiB
  const size_t US_OFF = XG_OFF + (size_t)MROWS * C * 2;
  const size_t NEED = US_OFF + (size_t)MROWS * C * 2;

  prep_weights<<<256, 256, 0, stream>>>(Wp, Wb, Wg, Wd, wgt);

  if (ws_size >= NEED) {
    short* xg = (short*)((char*)d_ws + XG_OFF);
    short* uS = (short*)((char*)d_ws + US_OFF);
    k1_proj<<<MROWS / 64, 256, 0, stream>>>(xe, wgt, bp, bb, xg, uS);
    k2_scan<<<NBE, 256, 0, stream>>>(ap, uS);
    k3_tile64<<<MROWS / 64, 256, 0, stream>>>(wgt, xg, uS, bg, bd, gamma, beta,
                                              rmean, rvar, out);
  } else {
    fused_fallback<<<NBE, 512, 0, stream>>>(xe, wgt, bp, ap, bb, bg, bd, gamma,
                                            beta, rmean, rvar, out);
  }
}